// Round 1
// baseline (994.437 us; speedup 1.0000x reference)
//
#include <hip/hip_runtime.h>

// Problem constants: B=16, C=128, H=W=64, N=4096, M=1024, CQ=C/8=16, CV=C/2=64.
// ws layout (floats): q [16][16][4096] @0 (1048576), k [16][16][1024] @1048576
// (262144), v [16][64][1024] @1310720 (1048576). Total 9.4 MB < ws_size.

#define B_ 16
#define CIN 128
#define NPOS 4096   // 64*64
#define MPOS 1024   // 32*32
#define CQ 16
#define CV 64

// ---------------------------------------------------------------------------
// Kernel 1: fused q/k/v 1x1-conv projections + 2x2 maxpool for k,v.
// One thread per spatial position. Zigzag lane mapping: lanes 4t..4t+3 form
// one 2x2 pool block, so pooling is __shfl_xor(1) + __shfl_xor(2) in-wave.
// ---------------------------------------------------------------------------
__global__ __launch_bounds__(256) void proj_kernel(
    const float* __restrict__ x,  const float* __restrict__ wq,
    const float* __restrict__ wk, const float* __restrict__ wv,
    float* __restrict__ qo, float* __restrict__ ko, float* __restrict__ vo)
{
  const int b  = blockIdx.y;
  const int i  = blockIdx.x * 256 + threadIdx.x;   // 0..4095
  const int q2 = i >> 2;                           // pooled index 0..1023
  const int r  = i & 3;
  const int h  = ((q2 >> 5) << 1) | (r >> 1);
  const int w  = ((q2 & 31) << 1) | (r & 1);
  const int n  = (h << 6) | w;

  const float* xb = x + (size_t)b * CIN * NPOS + n;

  float acc[96];
  #pragma unroll
  for (int o = 0; o < 96; ++o) acc[o] = 0.f;

  #pragma unroll 1
  for (int c0 = 0; c0 < CIN; c0 += 16) {
    float xr[16];
    #pragma unroll
    for (int j = 0; j < 16; ++j)
      xr[j] = xb[(size_t)(c0 + j) * NPOS];

#define WBLOCK(WPTR, NOUT, ABASE)                                    \
    _Pragma("unroll")                                                \
    for (int o = 0; o < (NOUT); ++o) {                               \
      const float* wr = (WPTR) + o * CIN + c0;                       \
      _Pragma("unroll")                                              \
      for (int j = 0; j < 16; j += 4) {                              \
        float4 w4 = *(const float4*)(wr + j);                        \
        acc[(ABASE) + o] = fmaf(w4.x, xr[j+0], acc[(ABASE) + o]);    \
        acc[(ABASE) + o] = fmaf(w4.y, xr[j+1], acc[(ABASE) + o]);    \
        acc[(ABASE) + o] = fmaf(w4.z, xr[j+2], acc[(ABASE) + o]);    \
        acc[(ABASE) + o] = fmaf(w4.w, xr[j+3], acc[(ABASE) + o]);    \
      }                                                              \
    }

    WBLOCK(wq, 16, 0)
    WBLOCK(wk, 16, 16)
    WBLOCK(wv, 64, 32)
#undef WBLOCK
  }

  // q: store directly (no pooling)
  #pragma unroll
  for (int o = 0; o < CQ; ++o)
    qo[((size_t)b * CQ + o) * NPOS + n] = acc[o];

  // k, v: 2x2 maxpool across the 4-lane group
  #pragma unroll
  for (int o = 16; o < 96; ++o) {
    float m = acc[o];
    m = fmaxf(m, __shfl_xor(m, 1));
    m = fmaxf(m, __shfl_xor(m, 2));
    acc[o] = m;
  }
  if (r == 0) {
    #pragma unroll
    for (int o = 0; o < CQ; ++o)
      ko[((size_t)b * CQ + o) * MPOS + q2] = acc[16 + o];
    #pragma unroll
    for (int o = 0; o < CV; ++o)
      vo[((size_t)b * CV + o) * MPOS + q2] = acc[32 + o];
  }
}

// ---------------------------------------------------------------------------
// Kernel 2: fused attention (QK^T -> softmax -> PV) + wo projection +
// gamma*o + x residual. One thread per query; K tile in LDS (uniform
// broadcast reads); V/wo from global (L2-resident, wave-uniform addresses).
// No max-subtraction: logits ~N(0,1.3); fp32 exp safe to logit ~88.
// ---------------------------------------------------------------------------
__global__ __launch_bounds__(256) void attn_kernel(
    const float* __restrict__ q, const float* __restrict__ k,
    const float* __restrict__ v, const float* __restrict__ wo,
    const float* __restrict__ x, const float* __restrict__ gamma,
    float* __restrict__ out)
{
  __shared__ float k_lds[CQ * MPOS];   // 64 KB

  const int b = blockIdx.y;
  const int n = blockIdx.x * 256 + threadIdx.x;

  const float* kb = k + (size_t)b * CQ * MPOS;
  for (int idx = threadIdx.x; idx < (CQ * MPOS / 4); idx += 256)
    *(float4*)&k_lds[idx * 4] = *(const float4*)&kb[idx * 4];
  __syncthreads();

  float qr[CQ];
  #pragma unroll
  for (int c = 0; c < CQ; ++c)
    qr[c] = q[((size_t)b * CQ + c) * NPOS + n];

  float acc[CV];
  #pragma unroll
  for (int c2 = 0; c2 < CV; ++c2) acc[c2] = 0.f;
  float l = 0.f;

  const float* vb = v + (size_t)b * CV * MPOS;

  #pragma unroll 1
  for (int m0 = 0; m0 < MPOS; m0 += 4) {
    float lg0 = 0.f, lg1 = 0.f, lg2 = 0.f, lg3 = 0.f;
    #pragma unroll
    for (int c = 0; c < CQ; ++c) {
      const float qc = qr[c];
      float4 kk = *(const float4*)&k_lds[c * MPOS + m0];
      lg0 = fmaf(qc, kk.x, lg0);
      lg1 = fmaf(qc, kk.y, lg1);
      lg2 = fmaf(qc, kk.z, lg2);
      lg3 = fmaf(qc, kk.w, lg3);
    }
    const float p0 = __expf(lg0), p1 = __expf(lg1);
    const float p2 = __expf(lg2), p3 = __expf(lg3);
    l += (p0 + p1) + (p2 + p3);
    #pragma unroll
    for (int c2 = 0; c2 < CV; ++c2) {
      float4 vv = *(const float4*)&vb[c2 * MPOS + m0];
      acc[c2] = fmaf(p0, vv.x, acc[c2]);
      acc[c2] = fmaf(p1, vv.y, acc[c2]);
      acc[c2] = fmaf(p2, vv.z, acc[c2]);
      acc[c2] = fmaf(p3, vv.w, acc[c2]);
    }
  }

  const float inv = 1.f / l;
  #pragma unroll
  for (int c2 = 0; c2 < CV; ++c2) acc[c2] *= inv;

  const float g = gamma[0];
  const float* xb = x + (size_t)b * CIN * NPOS + n;
  float* ob = out + (size_t)b * CIN * NPOS + n;

  #pragma unroll 1
  for (int co = 0; co < CIN; ++co) {
    float rsum = 0.f;
    const float* wr = wo + co * CV;
    #pragma unroll
    for (int c2 = 0; c2 < CV; c2 += 4) {
      float4 w4 = *(const float4*)(wr + c2);
      rsum = fmaf(w4.x, acc[c2+0], rsum);
      rsum = fmaf(w4.y, acc[c2+1], rsum);
      rsum = fmaf(w4.z, acc[c2+2], rsum);
      rsum = fmaf(w4.w, acc[c2+3], rsum);
    }
    ob[(size_t)co * NPOS] = g * rsum + xb[(size_t)co * NPOS];
  }
}

extern "C" void kernel_launch(void* const* d_in, const int* in_sizes, int n_in,
                              void* d_out, int out_size, void* d_ws, size_t ws_size,
                              hipStream_t stream) {
  const float* x     = (const float*)d_in[0];
  const float* wq    = (const float*)d_in[1];
  const float* wk    = (const float*)d_in[2];
  const float* wv    = (const float*)d_in[3];
  const float* wo    = (const float*)d_in[4];
  const float* gamma = (const float*)d_in[5];
  float* out = (float*)d_out;

  float* ws = (float*)d_ws;
  float* qo = ws;                                  // 1048576 floats
  float* ko = ws + 1048576;                        // 262144 floats
  float* vo = ws + 1048576 + 262144;               // 1048576 floats

  dim3 blk(256);
  dim3 grd(NPOS / 256, B_);   // 16 x 16
  proj_kernel<<<grd, blk, 0, stream>>>(x, wq, wk, wv, qo, ko, vo);
  attn_kernel<<<grd, blk, 0, stream>>>(qo, ko, vo, wo, x, gamma, out);
}

// Round 2
// 578.505 us; speedup vs baseline: 1.7190x; 1.7190x over previous
//
#include <hip/hip_runtime.h>

// B=16, C=128, H=W=64, N=4096, M=1024, CQ=16, CV=64.
// ws layout (floats): q [16][16][4096] @0, k [16][16][1024] @1048576,
// v [16][64][1024] @1310720.

#define B_ 16
#define CIN 128
#define NPOS 4096
#define MPOS 1024
#define CQ 16
#define CV 64

// ---------------------------------------------------------------------------
// Kernel 1: q/k/v 1x1 conv + 2x2 maxpool (k,v). 1024 blocks, 4 waves/block.
// Block handles 64 zigzag positions (4-lane groups = 2x2 pool blocks);
// x tile staged in LDS; waves split the 96 output channels 24-each.
// ---------------------------------------------------------------------------
__global__ __launch_bounds__(256) void proj_kernel(
    const float* __restrict__ x,  const float* __restrict__ wq,
    const float* __restrict__ wk, const float* __restrict__ wv,
    float* __restrict__ qo, float* __restrict__ ko, float* __restrict__ vo)
{
  __shared__ float x_lds[CIN * 64];   // 32 KB: [c][64 local pos]

  const int b   = blockIdx.y;
  const int tid = threadIdx.x;
  const int j   = tid & 63;          // local position
  const int g   = tid >> 6;          // wave id = channel group

  const int q2_0 = blockIdx.x * 16;          // first pooled index
  const int h0   = (q2_0 >> 5) << 1;         // first full-res row
  const int w0   = (q2_0 & 31) << 1;         // first full-res col

  const float* xb = x + (size_t)b * CIN * NPOS;

  // stage x tile: per channel, 2 rows x 32 cols -> x_lds[c][s*32+col]
  #pragma unroll
  for (int i = 0; i < 8; ++i) {
    const int f    = tid + i * 256;          // 0..2047 float4 index
    const int c    = f >> 4;
    const int quad = f & 15;
    const int s    = quad >> 3;
    const int col4 = (quad & 7) << 2;
    const float4 val = *(const float4*)&xb[(size_t)c * NPOS + (h0 + s) * 64 + w0 + col4];
    *(float4*)&x_lds[c * 64 + s * 32 + col4] = val;
  }
  __syncthreads();

  const int r  = j & 3;
  const int j2 = ((r >> 1) << 5) | ((j >> 2) << 1) | (r & 1);  // local lds pos
  const int n  = (h0 + (j2 >> 5)) * 64 + w0 + (j2 & 31);       // global pos
  const int q2 = q2_0 + (j >> 2);                              // pooled idx

  // weight row pointers for this wave's 24 outputs
  const float* wrow[24];
  if (g == 0) {
    #pragma unroll
    for (int o = 0; o < 16; ++o) wrow[o] = wq + o * CIN;
    #pragma unroll
    for (int o = 0; o < 8; ++o)  wrow[16 + o] = wk + o * CIN;
  } else if (g == 1) {
    #pragma unroll
    for (int o = 0; o < 8; ++o)  wrow[o] = wk + (8 + o) * CIN;
    #pragma unroll
    for (int o = 0; o < 16; ++o) wrow[8 + o] = wv + o * CIN;
  } else if (g == 2) {
    #pragma unroll
    for (int o = 0; o < 24; ++o) wrow[o] = wv + (16 + o) * CIN;
  } else {
    #pragma unroll
    for (int o = 0; o < 24; ++o) wrow[o] = wv + (40 + o) * CIN;
  }

  float acc[24];
  #pragma unroll
  for (int o = 0; o < 24; ++o) acc[o] = 0.f;

  #pragma unroll 1
  for (int c0 = 0; c0 < CIN; c0 += 16) {
    float xr[16];
    #pragma unroll
    for (int cc = 0; cc < 16; ++cc)
      xr[cc] = x_lds[(c0 + cc) * 64 + j2];
    #pragma unroll
    for (int o = 0; o < 24; ++o) {
      const float* wr = wrow[o] + c0;
      #pragma unroll
      for (int cc = 0; cc < 16; cc += 4) {
        float4 w4 = *(const float4*)(wr + cc);
        acc[o] = fmaf(w4.x, xr[cc + 0], acc[o]);
        acc[o] = fmaf(w4.y, xr[cc + 1], acc[o]);
        acc[o] = fmaf(w4.z, xr[cc + 2], acc[o]);
        acc[o] = fmaf(w4.w, xr[cc + 3], acc[o]);
      }
    }
  }

#define POOL(v_) ({ float m_ = (v_); m_ = fmaxf(m_, __shfl_xor(m_, 1)); \
                    m_ = fmaxf(m_, __shfl_xor(m_, 2)); m_; })

  if (g == 0) {
    #pragma unroll
    for (int o = 0; o < 16; ++o)
      qo[((size_t)b * CQ + o) * NPOS + n] = acc[o];
    #pragma unroll
    for (int o = 0; o < 8; ++o) {
      float m = POOL(acc[16 + o]);
      if (r == 0) ko[((size_t)b * CQ + o) * MPOS + q2] = m;
    }
  } else if (g == 1) {
    #pragma unroll
    for (int o = 0; o < 8; ++o) {
      float m = POOL(acc[o]);
      if (r == 0) ko[((size_t)b * CQ + 8 + o) * MPOS + q2] = m;
    }
    #pragma unroll
    for (int o = 0; o < 16; ++o) {
      float m = POOL(acc[8 + o]);
      if (r == 0) vo[((size_t)b * CV + o) * MPOS + q2] = m;
    }
  } else if (g == 2) {
    #pragma unroll
    for (int o = 0; o < 24; ++o) {
      float m = POOL(acc[o]);
      if (r == 0) vo[((size_t)b * CV + 16 + o) * MPOS + q2] = m;
    }
  } else {
    #pragma unroll
    for (int o = 0; o < 24; ++o) {
      float m = POOL(acc[o]);
      if (r == 0) vo[((size_t)b * CV + 40 + o) * MPOS + q2] = m;
    }
  }
#undef POOL
}

// ---------------------------------------------------------------------------
// Kernel 2: fused attention + wo + residual. 1024 blocks, 4 waves/block.
// Block = 64 queries; wave g owns V channels [g*16, g*16+16). K/V staged in
// LDS per M-tile of 128. o goes through LDS (aliases tile region) for the
// wo epilogue where wave g computes out channels [g*32, g*32+32).
// ---------------------------------------------------------------------------
__global__ __launch_bounds__(256) void attn_kernel(
    const float* __restrict__ q, const float* __restrict__ k,
    const float* __restrict__ v, const float* __restrict__ wo,
    const float* __restrict__ x, const float* __restrict__ gamma,
    float* __restrict__ out)
{
  __shared__ float lds[10240];   // 40 KB: k[16][128] @0, v[64][128] @2048; o reuses @0

  const int b   = blockIdx.y;
  const int tid = threadIdx.x;
  const int qi  = tid & 63;
  const int g   = tid >> 6;
  const int n   = blockIdx.x * 64 + qi;

  const float* qb = q + (size_t)b * CQ * NPOS;
  const float* kb = k + (size_t)b * CQ * MPOS;
  const float* vb = v + (size_t)b * CV * MPOS;

  float qr[CQ];
  #pragma unroll
  for (int c = 0; c < CQ; ++c)
    qr[c] = qb[(size_t)c * NPOS + n];

  float acc[16];
  #pragma unroll
  for (int jj = 0; jj < 16; ++jj) acc[jj] = 0.f;
  float l = 0.f;

  float* k_t = lds;
  float* v_t = lds + 2048;

  #pragma unroll 1
  for (int t = 0; t < 8; ++t) {
    // stage K tile (16x128) and V tile (64x128)
    #pragma unroll
    for (int i = 0; i < 2; ++i) {
      const int f = tid + i * 256;
      const int row = f >> 5, c4 = (f & 31) << 2;
      *(float4*)&k_t[row * 128 + c4] =
          *(const float4*)&kb[(size_t)row * MPOS + t * 128 + c4];
    }
    #pragma unroll
    for (int i = 0; i < 8; ++i) {
      const int f = tid + i * 256;
      const int row = f >> 5, c4 = (f & 31) << 2;
      *(float4*)&v_t[row * 128 + c4] =
          *(const float4*)&vb[(size_t)row * MPOS + t * 128 + c4];
    }
    __syncthreads();

    #pragma unroll 1
    for (int m0 = 0; m0 < 128; m0 += 4) {
      float lg0 = 0.f, lg1 = 0.f, lg2 = 0.f, lg3 = 0.f;
      #pragma unroll
      for (int c = 0; c < CQ; ++c) {
        const float qc = qr[c];
        float4 kk = *(const float4*)&k_t[c * 128 + m0];
        lg0 = fmaf(qc, kk.x, lg0);
        lg1 = fmaf(qc, kk.y, lg1);
        lg2 = fmaf(qc, kk.z, lg2);
        lg3 = fmaf(qc, kk.w, lg3);
      }
      const float p0 = __expf(lg0), p1 = __expf(lg1);
      const float p2 = __expf(lg2), p3 = __expf(lg3);
      l += (p0 + p1) + (p2 + p3);
      #pragma unroll
      for (int jj = 0; jj < 16; ++jj) {
        float4 vv = *(const float4*)&v_t[(g * 16 + jj) * 128 + m0];
        acc[jj] = fmaf(p0, vv.x, acc[jj]);
        acc[jj] = fmaf(p1, vv.y, acc[jj]);
        acc[jj] = fmaf(p2, vv.z, acc[jj]);
        acc[jj] = fmaf(p3, vv.w, acc[jj]);
      }
    }
    __syncthreads();
  }

  // normalized o -> LDS (aliases tile region; all compute done per barrier)
  const float inv = 1.f / l;
  float* o_lds = lds;   // [64 c2][64 qi]
  #pragma unroll
  for (int jj = 0; jj < 16; ++jj)
    o_lds[(g * 16 + jj) * 64 + qi] = acc[jj] * inv;
  __syncthreads();

  float org[CV];
  #pragma unroll
  for (int c2 = 0; c2 < CV; ++c2)
    org[c2] = o_lds[c2 * 64 + qi];

  const float gm = gamma[0];
  const float* xb = x + (size_t)b * CIN * NPOS + n;
  float* ob = out + (size_t)b * CIN * NPOS + n;

  #pragma unroll 1
  for (int oi = 0; oi < 32; ++oi) {
    const int co = g * 32 + oi;
    const float* wr = wo + co * CV;
    float s = 0.f;
    #pragma unroll
    for (int c2 = 0; c2 < CV; c2 += 4) {
      float4 w4 = *(const float4*)(wr + c2);
      s = fmaf(w4.x, org[c2 + 0], s);
      s = fmaf(w4.y, org[c2 + 1], s);
      s = fmaf(w4.z, org[c2 + 2], s);
      s = fmaf(w4.w, org[c2 + 3], s);
    }
    ob[(size_t)co * NPOS] = gm * s + xb[(size_t)co * NPOS];
  }
}

extern "C" void kernel_launch(void* const* d_in, const int* in_sizes, int n_in,
                              void* d_out, int out_size, void* d_ws, size_t ws_size,
                              hipStream_t stream) {
  const float* x     = (const float*)d_in[0];
  const float* wq    = (const float*)d_in[1];
  const float* wk    = (const float*)d_in[2];
  const float* wv    = (const float*)d_in[3];
  const float* wo    = (const float*)d_in[4];
  const float* gamma = (const float*)d_in[5];
  float* out = (float*)d_out;

  float* ws = (float*)d_ws;
  float* qo = ws;
  float* ko = ws + 1048576;
  float* vo = ws + 1048576 + 262144;

  dim3 blk(256);
  dim3 grd(64, B_);   // 64 pos-blocks x 16 batches
  proj_kernel<<<grd, blk, 0, stream>>>(x, wq, wk, wv, qo, ko, vo);
  attn_kernel<<<grd, blk, 0, stream>>>(qo, ko, vo, wo, x, gamma, out);
}

// Round 3
// 153.179 us; speedup vs baseline: 6.4920x; 3.7767x over previous
//
#include <hip/hip_runtime.h>

// B=16, C=128, H=W=64, N=4096 (p-space, zigzag), M=1024, CQ=16, CV=64.
// All GEMM-shaped work on v_mfma_f32_32x32x16_bf16.
// ws (shorts): xT[16][4096][128] @0, qT[16][4096][16] @8388608,
//              kT[16][1024][16] @9437184, v[16][64][1024] @9699328. ~21.5 MB.

#define LOG2E 1.4426950408889634f

typedef __attribute__((ext_vector_type(8)))  short bf16x8;
typedef __attribute__((ext_vector_type(16))) float f32x16;

static __device__ __forceinline__ unsigned cvt_pk_bf16(float a, float b) {
  unsigned r;
  asm("v_cvt_pk_bf16_f32 %0, %1, %2" : "=v"(r) : "v"(a), "v"(b));
  return r;
}
static __device__ __forceinline__ void perm32swap(unsigned& a, unsigned& b) {
  asm volatile("v_permlane32_swap_b32 %0, %1" : "+v"(a), "+v"(b));
}
static __device__ __forceinline__ float fexp2(float x) {
  float r; asm("v_exp_f32 %0, %1" : "=v"(r) : "v"(x)); return r;
}
static __device__ __forceinline__ short f2bf(float f) {   // RTNE
  unsigned u = __float_as_uint(f);
  u = (u + 0x7FFFu + ((u >> 16) & 1u)) >> 16;
  return (short)u;
}
static __device__ __forceinline__ bf16x8 pack4(unsigned u0, unsigned u1,
                                               unsigned u2, unsigned u3) {
  union { bf16x8 v; unsigned u[4]; } r;
  r.u[0] = u0; r.u[1] = u1; r.u[2] = u2; r.u[3] = u3;
  return r.v;
}

// ---------------------------------------------------------------------------
// Kernel 0: x [b][128c][4096n] fp32 -> xT [b][4096p][128c] bf16, p = zigzag(n).
// Block: one (b, c-half 64, h-row); classic LDS transpose.
// ---------------------------------------------------------------------------
__global__ __launch_bounds__(256) void transpose_kernel(
    const float* __restrict__ x, short* __restrict__ xT)
{
  __shared__ float xl[64][68];
  const int b = blockIdx.z, c0 = blockIdx.y * 64, h = blockIdx.x;
  const int t = threadIdx.x;

  {
    const int c = t >> 2, w0 = (t & 3) * 16;
    const float* rp = x + ((size_t)(b * 128 + c0 + c)) * 4096 + h * 64 + w0;
    #pragma unroll
    for (int i = 0; i < 4; ++i)
      *(float4*)&xl[c][w0 + i * 4] = *(const float4*)(rp + i * 4);
  }
  __syncthreads();

  const int w = t >> 2, cc0 = (t & 3) * 16;
  const int p = ((h >> 1) << 7) + ((h & 1) << 1) + ((w >> 1) << 2) + (w & 1);
  short* dst = xT + ((size_t)b * 4096 + p) * 128 + c0 + cc0;

  bf16x8 lo, hi;
  #pragma unroll
  for (int j = 0; j < 8; ++j) lo[j] = f2bf(xl[cc0 + j][w]);
  #pragma unroll
  for (int j = 0; j < 8; ++j) hi[j] = f2bf(xl[cc0 + 8 + j][w]);
  *(bf16x8*)dst = lo;
  *(bf16x8*)(dst + 8) = hi;
}

// ---------------------------------------------------------------------------
// Kernel 1: MFMA proj. Block = 4 waves x 32 p = 128 p. D[p][ch]=xT*W.
// ch-tile0 = q(0..15)|k(0..15), tiles 1,2 = v. Pool = in-lane reg-quad max.
// q scaled by log2e (softmax exp becomes raw v_exp_f32 downstream).
// ---------------------------------------------------------------------------
__global__ __launch_bounds__(256) void proj_kernel(
    const short* __restrict__ xT, const float* __restrict__ wq,
    const float* __restrict__ wk, const float* __restrict__ wv,
    short* __restrict__ qT, short* __restrict__ kT, short* __restrict__ vO)
{
  __shared__ short q_s[128][16];
  __shared__ short k_s[32][16];
  __shared__ short v_s[64][32];

  const int b = blockIdx.y, t = threadIdx.x;
  const int wid = t >> 6, lane = t & 63;
  const int l31 = lane & 31, hi = lane >> 5;
  const int p0 = blockIdx.x * 128;
  const int pw = p0 + wid * 32;

  const float* w0p = (l31 < 16) ? (wq + l31 * 128) : (wk + (l31 - 16) * 128);
  const float* w1p = wv + l31 * 128;
  const float* w2p = wv + (32 + l31) * 128;

  const short* xrow = xT + ((size_t)b * 4096 + pw + l31) * 128 + hi * 8;

  f32x16 acc0, acc1, acc2;
  #pragma unroll
  for (int j = 0; j < 16; ++j) { acc0[j] = 0.f; acc1[j] = 0.f; acc2[j] = 0.f; }

  #pragma unroll
  for (int cc = 0; cc < 8; ++cc) {
    const int c0 = cc * 16;
    bf16x8 a = *(const bf16x8*)(xrow + c0);
#define LOADW(PTR)                                                          \
    ({ const float* r_ = (PTR) + c0 + hi * 8;                               \
       float4 f0 = *(const float4*)r_, f1 = *(const float4*)(r_ + 4);       \
       pack4(cvt_pk_bf16(f0.x, f0.y), cvt_pk_bf16(f0.z, f0.w),              \
             cvt_pk_bf16(f1.x, f1.y), cvt_pk_bf16(f1.z, f1.w)); })
    bf16x8 b0 = LOADW(w0p), b1 = LOADW(w1p), b2 = LOADW(w2p);
#undef LOADW
    acc0 = __builtin_amdgcn_mfma_f32_32x32x16_bf16(a, b0, acc0, 0, 0, 0);
    acc1 = __builtin_amdgcn_mfma_f32_32x32x16_bf16(a, b1, acc1, 0, 0, 0);
    acc2 = __builtin_amdgcn_mfma_f32_32x32x16_bf16(a, b2, acc2, 0, 0, 0);
  }

  // rows: p_local = (r&3) + 8*(r>>2) + 4*hi; pool quad g: regs 4g..4g+3 ->
  // pooled q2_local = wid*8 + 2g + hi.
  if (l31 < 16) {
    #pragma unroll
    for (int r = 0; r < 16; ++r) {
      const int pl = (r & 3) + 8 * (r >> 2) + 4 * hi;
      q_s[wid * 32 + pl][l31] = f2bf(acc0[r] * LOG2E);
    }
  } else {
    #pragma unroll
    for (int g = 0; g < 4; ++g) {
      float m = fmaxf(fmaxf(acc0[4*g], acc0[4*g+1]), fmaxf(acc0[4*g+2], acc0[4*g+3]));
      k_s[wid * 8 + 2 * g + hi][l31 - 16] = f2bf(m);
    }
  }
  #pragma unroll
  for (int g = 0; g < 4; ++g) {
    float m1 = fmaxf(fmaxf(acc1[4*g], acc1[4*g+1]), fmaxf(acc1[4*g+2], acc1[4*g+3]));
    float m2 = fmaxf(fmaxf(acc2[4*g], acc2[4*g+1]), fmaxf(acc2[4*g+2], acc2[4*g+3]));
    v_s[l31][wid * 8 + 2 * g + hi]      = f2bf(m1);
    v_s[32 + l31][wid * 8 + 2 * g + hi] = f2bf(m2);
  }
  __syncthreads();

  {
    const int row = t >> 1, half = t & 1;
    *(bf16x8*)(qT + ((size_t)b * 4096 + p0 + row) * 16 + half * 8) =
        *(const bf16x8*)&q_s[row][half * 8];
  }
  if (t < 64) {
    const int row = t >> 1, half = t & 1;
    *(bf16x8*)(kT + ((size_t)b * 1024 + blockIdx.x * 32 + row) * 16 + half * 8) =
        *(const bf16x8*)&k_s[row][half * 8];
  }
  {
    const int c2 = t >> 2, qo = (t & 3) * 8;
    *(bf16x8*)(vO + ((size_t)b * 64 + c2) * 1024 + blockIdx.x * 32 + qo) =
        *(const bf16x8*)&v_s[c2][qo];
  }
}

// ---------------------------------------------------------------------------
// Kernel 2: flash attention + wo + residual, all MFMA. 4 waves x 32 q, no LDS,
// no barriers. S=mfma(K,Q) -> D[m][n]; P->bf16 via cvt_pk+permlane32_swap;
// PV + wo MFMA; out = gamma*o + x.
// ---------------------------------------------------------------------------
__global__ __launch_bounds__(256) void attn_kernel(
    const short* __restrict__ qT, const short* __restrict__ kT,
    const short* __restrict__ vO, const float* __restrict__ wo,
    const float* __restrict__ x, const float* __restrict__ gamma,
    float* __restrict__ out)
{
  const int b = blockIdx.y, t = threadIdx.x;
  const int wid = t >> 6, lane = t & 63;
  const int l31 = lane & 31, hi = lane >> 5;
  const int p = blockIdx.x * 128 + wid * 32 + l31;
  const int q2 = p >> 2, rr = p & 3;
  const int nsp = ((((q2 >> 5) << 1) | (rr >> 1)) << 6) | (((q2 & 31) << 1) | (rr & 1));

  const short* qTb = qT + (size_t)b * 4096 * 16;
  const short* kTb = kT + (size_t)b * 1024 * 16;
  const short* vb  = vO + (size_t)b * 64 * 1024;

  const bf16x8 qf = *(const bf16x8*)(qTb + (size_t)p * 16 + hi * 8);

  f32x16 z, o0, o1;
  #pragma unroll
  for (int j = 0; j < 16; ++j) { z[j] = 0.f; o0[j] = 0.f; o1[j] = 0.f; }
  float l = 0.f;

  #pragma unroll 2
  for (int mt = 0; mt < 32; ++mt) {
    const int m0 = mt * 32;
    const bf16x8 kf = *(const bf16x8*)(kTb + (size_t)(m0 + l31) * 16 + hi * 8);
    const size_t vr0 = (size_t)l31 * 1024 + m0 + hi * 8;
    const size_t vr1 = (size_t)(32 + l31) * 1024 + m0 + hi * 8;
    const bf16x8 v00 = *(const bf16x8*)(vb + vr0);
    const bf16x8 v01 = *(const bf16x8*)(vb + vr0 + 16);
    const bf16x8 v10 = *(const bf16x8*)(vb + vr1);
    const bf16x8 v11 = *(const bf16x8*)(vb + vr1 + 16);

    f32x16 s = __builtin_amdgcn_mfma_f32_32x32x16_bf16(kf, qf, z, 0, 0, 0);

    float pe[16];
    #pragma unroll
    for (int j = 0; j < 16; ++j) pe[j] = fexp2(s[j]);
    l += ((pe[0] + pe[1]) + (pe[2] + pe[3])) + ((pe[4] + pe[5]) + (pe[6] + pe[7]))
       + ((pe[8] + pe[9]) + (pe[10] + pe[11])) + ((pe[12] + pe[13]) + (pe[14] + pe[15]));

    unsigned a0 = cvt_pk_bf16(pe[0], pe[1]),  a1 = cvt_pk_bf16(pe[2], pe[3]);
    unsigned a2 = cvt_pk_bf16(pe[4], pe[5]),  a3 = cvt_pk_bf16(pe[6], pe[7]);
    perm32swap(a0, a2); perm32swap(a1, a3);
    const bf16x8 P0 = pack4(a0, a1, a2, a3);
    unsigned c0 = cvt_pk_bf16(pe[8], pe[9]),  c1 = cvt_pk_bf16(pe[10], pe[11]);
    unsigned c2 = cvt_pk_bf16(pe[12], pe[13]), c3 = cvt_pk_bf16(pe[14], pe[15]);
    perm32swap(c0, c2); perm32swap(c1, c3);
    const bf16x8 P1 = pack4(c0, c1, c2, c3);

    o0 = __builtin_amdgcn_mfma_f32_32x32x16_bf16(v00, P0, o0, 0, 0, 0);
    o0 = __builtin_amdgcn_mfma_f32_32x32x16_bf16(v01, P1, o0, 0, 0, 0);
    o1 = __builtin_amdgcn_mfma_f32_32x32x16_bf16(v10, P0, o1, 0, 0, 0);
    o1 = __builtin_amdgcn_mfma_f32_32x32x16_bf16(v11, P1, o1, 0, 0, 0);
  }

  l += __shfl_xor(l, 32);
  const float inv = 1.0f / l;

  float on[32];
  #pragma unroll
  for (int j = 0; j < 16; ++j) { on[j] = o0[j] * inv; on[16 + j] = o1[j] * inv; }

  bf16x8 ofr[4];
  #pragma unroll
  for (int ck = 0; ck < 4; ++ck) {
    const int base = (ck >> 1) * 16 + (ck & 1) * 8;
    unsigned a0 = cvt_pk_bf16(on[base + 0], on[base + 1]);
    unsigned a1 = cvt_pk_bf16(on[base + 2], on[base + 3]);
    unsigned a2 = cvt_pk_bf16(on[base + 4], on[base + 5]);
    unsigned a3 = cvt_pk_bf16(on[base + 6], on[base + 7]);
    perm32swap(a0, a2); perm32swap(a1, a3);
    ofr[ck] = pack4(a0, a1, a2, a3);
  }

  const float g = gamma[0];
  const float* xb = x + ((size_t)b * 128) * 4096 + nsp;
  float* ob = out + ((size_t)b * 128) * 4096 + nsp;

  #pragma unroll 1
  for (int cot = 0; cot < 4; ++cot) {
    f32x16 acc;
    #pragma unroll
    for (int j = 0; j < 16; ++j) acc[j] = 0.f;
    #pragma unroll
    for (int ck = 0; ck < 4; ++ck) {
      const float* wr = wo + (size_t)(cot * 32 + l31) * 64 + ck * 16 + hi * 8;
      float4 f0 = *(const float4*)wr;
      float4 f1 = *(const float4*)(wr + 4);
      bf16x8 wf = pack4(cvt_pk_bf16(f0.x, f0.y), cvt_pk_bf16(f0.z, f0.w),
                        cvt_pk_bf16(f1.x, f1.y), cvt_pk_bf16(f1.z, f1.w));
      acc = __builtin_amdgcn_mfma_f32_32x32x16_bf16(wf, ofr[ck], acc, 0, 0, 0);
    }
    #pragma unroll
    for (int r = 0; r < 16; ++r) {
      const int co = cot * 32 + (r & 3) + 8 * (r >> 2) + 4 * hi;
      ob[(size_t)co * 4096] = g * acc[r] + xb[(size_t)co * 4096];
    }
  }
}

extern "C" void kernel_launch(void* const* d_in, const int* in_sizes, int n_in,
                              void* d_out, int out_size, void* d_ws, size_t ws_size,
                              hipStream_t stream) {
  const float* x     = (const float*)d_in[0];
  const float* wq    = (const float*)d_in[1];
  const float* wk    = (const float*)d_in[2];
  const float* wv    = (const float*)d_in[3];
  const float* wo    = (const float*)d_in[4];
  const float* gamma = (const float*)d_in[5];
  float* out = (float*)d_out;

  short* ws = (short*)d_ws;
  short* xT = ws;                 // 16*4096*128
  short* qT = ws + 8388608;       // 16*4096*16
  short* kT = ws + 9437184;       // 16*1024*16
  short* vO = ws + 9699328;       // 16*64*1024

  transpose_kernel<<<dim3(64, 2, 16), 256, 0, stream>>>(x, xT);
  proj_kernel<<<dim3(32, 16), 256, 0, stream>>>(xT, wq, wk, wv, qT, kT, vO);
  attn_kernel<<<dim3(32, 16), 256, 0, stream>>>(qT, kT, vO, wo, x, gamma, out);
}